// Round 19
// baseline (10063.719 us; speedup 1.0000x reference)
//
#include <hip/hip_runtime.h>
#include <math.h>

typedef __attribute__((ext_vector_type(8))) short bf16x8;   // 8 bf16 (4 VGPR)
typedef __attribute__((ext_vector_type(4))) float f32x4;    // MFMA C/D

static constexpr int Tt = 1024;
static constexpr int Hh = 512;
static constexpr int Cc = 10;

static constexpr int NXCD = 8;       // XCDs; each runs an independent group
static constexpr int BPX  = 32;      // blocks (CUs) per XCD
static constexpr int UPB  = 16;      // hidden units per block (64 gate rows)
static constexpr int RPS  = 8;       // batch rows per stream (2 streams/XCD)
static constexpr int THREADS = 256;  // 4 waves; wave = 4-unit quad, all gates
static constexpr int GRID = 256;     // 1 block per CU (128 KB LDS forces it)

// ws bytes: [0,1024) flags0 | [1024,2048) flags1 | [2048,3072) rank counters
//           [4096,+256KB) h_hi[2][8][16][512] bf16 | then h_lo 256KB
static constexpr size_t WS_HHI_B  = 4096;
static constexpr size_t WS_HLO_B  = 4096 + 262144;
static constexpr size_t WS_ZERO_B = 4096 + 524288;

__device__ __forceinline__ unsigned short f2bf(float f) {
    unsigned u = __builtin_bit_cast(unsigned, f);
    return (unsigned short)((u + 0x7FFFu + ((u >> 16) & 1u)) >> 16);   // RNE
}
__device__ __forceinline__ float bf2f(unsigned short h) {
    unsigned u = ((unsigned)h) << 16;
    return __builtin_bit_cast(float, u);
}
__device__ __forceinline__ float dot4(float4 a, float4 b) {
    return a.x * b.x + a.y * b.y + a.z * b.z + a.w * b.w;
}
__device__ __forceinline__ float fsig(float x) {
    const float e = __builtin_amdgcn_exp2f(x * -1.44269504f);
    return __builtin_amdgcn_rcpf(1.0f + e);
}
__device__ __forceinline__ float ftanh(float x) {
    const float e = __builtin_amdgcn_exp2f(x * -2.88539008f);
    return 2.0f * __builtin_amdgcn_rcpf(1.0f + e) - 1.0f;
}

__global__ __launch_bounds__(THREADS, 1)
void lstm_fused(const float* __restrict__ x,
                const float* __restrict__ w_ih,
                const float* __restrict__ w_hh,
                const float* __restrict__ b_ih,
                const float* __restrict__ b_hh,
                const float* __restrict__ w_t,
                const float* __restrict__ w_fc,
                const float* __restrict__ b_fc,
                float* __restrict__ out,
                float* __restrict__ ws)
{
    const int tid  = threadIdx.x;
    const int lane = tid & 63;
    const int wv   = tid >> 6;          // wave = unit quad [wv*4, wv*4+4)
    const int frow = lane & 15;         // A row (gate*4+ul) / B batch col
    const int kgrp = lane >> 4;         // 8-elem K group within a 32-K step

    int* flags0   = (int*)ws;
    int* flags1   = (int*)ws + 256;
    int* counters = (int*)ws + 512;
    unsigned short* hg_hi = (unsigned short*)((char*)ws + WS_HHI_B);
    unsigned short* hg_lo = (unsigned short*)((char*)ws + WS_HLO_B);

    // LDS: W-hi 64K + W-lo 64K + xbuf 128B = ~128 KB -> 1 block/CU
    __shared__ __align__(16) short wls_hi[64 * 512];
    __shared__ __align__(16) short wls_lo[64 * 512];
    __shared__ float xbuf[2][16];             // split owner-emit partials
    int* xchg = (int*)xbuf;                   // init-time census exchange

    // ---- discover physical XCD, claim a rank ----
    if (tid == 0) {
        int xr;
        asm volatile("s_getreg_b32 %0, hwreg(20, 0, 32)" : "=s"(xr));
        const int xcd = xr & 7;
        xchg[0] = xcd;
        xchg[1] = atomicAdd(&counters[xcd * 32], 1) & 31;
    }
    __syncthreads();
    const int xcd  = xchg[0];
    const int rank = xchg[1];
    __syncthreads();
    const int fbase = xcd * BPX;

    // ---- preload + split w_hh into LDS; rows PERMUTED so each wave's read
    // pattern equals r17's proven conflict-free form: storage row
    // sr(g,u) = (u>>2)*16 + g*4 + (u&3); read row lrA = wv*16 + frow ----
    {
        #pragma unroll
        for (int it = 0; it < 16; ++it) {
            const int idx = it * 256 + tid;        // [0,4096): lr(64) x kg(64)
            const int lr = idx >> 6, kg = idx & 63;
            const int g = lr >> 4, u = lr & 15;
            const int grow = g * Hh + rank * UPB + u;
            const float4* src = (const float4*)(w_hh + (size_t)grow * Hh + kg * 8);
            const float4 f0 = src[0], f1 = src[1];
            const float f[8] = { f0.x, f0.y, f0.z, f0.w, f1.x, f1.y, f1.z, f1.w };
            bf16x8 vhi, vlo;
            #pragma unroll
            for (int j = 0; j < 8; ++j) {
                const unsigned short hb = f2bf(f[j]);
                vhi[j] = (short)hb;
                vlo[j] = (short)f2bf(f[j] - bf2f(hb));
            }
            const int sr  = ((u >> 2) * 16) + g * 4 + (u & 3);
            const int off = (sr * 1024 + kg * 16) ^ ((sr & 7) << 4);
            *(bf16x8*)((char*)wls_hi + off) = vhi;
            *(bf16x8*)((char*)wls_lo + off) = vlo;
        }
    }

    // ---- per-lane roles: after transpose, lane holds (unit wv*4+kgrp, batch frow)
    const int gj = rank * UPB + wv * 4 + kgrp;
    float wih_r[4], bias_r[4];
    #pragma unroll
    for (int g = 0; g < 4; ++g) {
        wih_r[g]  = w_ih[g * Hh + gj];
        bias_r[g] = b_ih[g * Hh + gj] + b_hh[g * Hh + gj];
    }
    float creg0 = 0.0f, creg1 = 0.0f;

    const bool owner  = (rank < 16);
    const int  ostrm  = rank >> 3;
    const int  gb_own = xcd * 16 + rank;
    float S1w[Cc], S2w[Cc], bfc_r[Cc];
    #pragma unroll
    for (int c = 0; c < Cc; ++c) { S1w[c] = 0.f; S2w[c] = 0.f; bfc_r[c] = b_fc[c]; }

    const int lrA    = wv * 16 + frow;
    const int aoff0  = lrA * 1024 + (kgrp << 4);
    const int xmaskA = (frow & 7) << 4;

    // per-wave flag poll (no block barrier needed): PROVEN buffer_inv form
    auto wave_poll = [&](int* fl, int target) {
        const volatile int* p = (const volatile int*)(fl + fbase + (lane & 31));
        int v = *p;
        while (__any(v < target)) {
            __builtin_amdgcn_s_sleep(1);
            asm volatile("buffer_inv\n\ts_waitcnt vmcnt(0)" ::: "memory");
            v = *p;
        }
        asm volatile("buffer_inv\n\ts_waitcnt vmcnt(0)" ::: "memory");
    };

    // split owner emit: wave wv computes projections p = 3wv..3wv+2 of row rank
    auto emit_partials = [&](const unsigned short* bh, const unsigned short* bl,
                             int slot) {
        const size_t rbase = (size_t)rank * Hh + lane * 8;
        const bf16x8 vh = *(const bf16x8*)(bh + rbase);
        const bf16x8 vl = *(const bf16x8*)(bl + rbase);
        float f[8];
        #pragma unroll
        for (int j = 0; j < 8; ++j)
            f[j] = bf2f((unsigned short)vh[j]) + bf2f((unsigned short)vl[j]);
        const float4 hA = make_float4(f[0], f[1], f[2], f[3]);
        const float4 hB = make_float4(f[4], f[5], f[6], f[7]);
        const float4* wt4 = (const float4*)w_t;
        const float4* wf4 = (const float4*)w_fc;
        float rp[3];
        #pragma unroll
        for (int q = 0; q < 3; ++q) {
            const int p = wv * 3 + q;
            const float4* base = (p == 0) ? wt4 + lane * 2
                               : (p == 1) ? wt4 + 128 + lane * 2
                               : wf4 + (size_t)(p - 2) * 128 + lane * 2;
            rp[q] = dot4(hA, base[0]) + dot4(hB, base[1]);
        }
        #pragma unroll
        for (int m = 1; m <= 32; m <<= 1)
            #pragma unroll
            for (int q = 0; q < 3; ++q)
                rp[q] += __shfl_xor(rp[q], m, 64);
        if (lane == 0) {
            xbuf[slot][wv * 3 + 0] = rp[0];
            xbuf[slot][wv * 3 + 1] = rp[1];
            xbuf[slot][wv * 3 + 2] = rp[2];
        }
    };

    // tid0: fold 12 partials, update S1w/S2w recurrence, store out(tout)
    auto out_update = [&](int tout, int slot) {
        const float a = xbuf[slot][0], b2 = xbuf[slot][1];
        float* po = out + ((size_t)gb_own * Tt + tout) * Cc;
        #pragma unroll
        for (int c = 0; c < Cc; ++c) {
            const float hw = xbuf[slot][2 + c];
            po[c] = hw + a * S1w[c] + S2w[c] + bfc_r[c];
            S1w[c] += hw;
            S2w[c] += b2 * hw;
        }
    };

    auto half_step = [&](int s, int t, int* fl, float& creg) {
        const int rb = (t - 1) & 1, wb = t & 1;
        const unsigned short* hbhi = hg_hi + (size_t)(rb * NXCD + xcd) * 16 * Hh;
        const unsigned short* hblo = hg_lo + (size_t)(rb * NXCD + xcd) * 16 * Hh;

        float xv = 0.f;                        // x independent: issue pre-poll
        if (frow < RPS) xv = x[(size_t)(xcd * 16 + s * RPS + frow) * Tt + (t - 1)];

        wave_poll(fl, t - 1);                  // per-wave release, no barrier

        // GEMM: 16 A-rows (4 gates x 4 units), full K; B direct from XCD L2
        f32x4 a0 = { 0.f, 0.f, 0.f, 0.f };
        f32x4 a1 = { 0.f, 0.f, 0.f, 0.f };
        f32x4 a2 = { 0.f, 0.f, 0.f, 0.f };
        {
            const int row16 = s * RPS + (frow & 7);
            const unsigned short* ph = hbhi + (size_t)row16 * Hh + kgrp * 8;
            const unsigned short* pl = hblo + (size_t)row16 * Hh + kgrp * 8;
            #pragma unroll
            for (int kk = 0; kk < 16; ++kk) {
                const int ao = (aoff0 + kk * 64) ^ xmaskA;
                const bf16x8 ahi = *(const bf16x8*)((const char*)wls_hi + ao);
                const bf16x8 alo = *(const bf16x8*)((const char*)wls_lo + ao);
                const bf16x8 bhi = *(const bf16x8*)(ph + kk * 32);
                const bf16x8 blo = *(const bf16x8*)(pl + kk * 32);
                a0 = __builtin_amdgcn_mfma_f32_16x16x32_bf16(ahi, bhi, a0, 0, 0, 0);
                a1 = __builtin_amdgcn_mfma_f32_16x16x32_bf16(ahi, blo, a1, 0, 0, 0);
                a2 = __builtin_amdgcn_mfma_f32_16x16x32_bf16(alo, bhi, a2, 0, 0, 0);
            }
        }
        float v0 = a0[0] + a1[0] + a2[0];
        float v1 = a0[1] + a1[1] + a2[1];
        float v2 = a0[2] + a1[2] + a2[2];
        float v3 = a0[3] + a1[3] + a2[3];

        // 4x4 transpose across lanes {b,b+16,b+32,b+48}: swap idx-bit with kgrp-bit
        {
            const bool k0 = ((kgrp & 1) == 0);
            const float t0 = __shfl_xor(v1, 16);
            const float t1 = __shfl_xor(v0, 16);
            const float t2 = __shfl_xor(v3, 16);
            const float t3 = __shfl_xor(v2, 16);
            v0 = k0 ? v0 : t0;
            v1 = k0 ? t1 : v1;
            v2 = k0 ? v2 : t2;
            v3 = k0 ? t3 : v3;
        }
        {
            const bool k1 = ((kgrp & 2) == 0);
            const float t0 = __shfl_xor(v2, 32);
            const float t1 = __shfl_xor(v3, 32);
            const float t2 = __shfl_xor(v0, 32);
            const float t3 = __shfl_xor(v1, 32);
            v0 = k1 ? v0 : t0;
            v1 = k1 ? v1 : t1;
            v2 = k1 ? t2 : v2;
            v3 = k1 ? t3 : v3;
        }
        // lane now holds gates i,f,g,o of (unit gj, batch frow) — inline LSTM
        {
            const float gi = v0 + xv * wih_r[0] + bias_r[0];
            const float gf = v1 + xv * wih_r[1] + bias_r[1];
            const float gg = v2 + xv * wih_r[2] + bias_r[2];
            const float go = v3 + xv * wih_r[3] + bias_r[3];
            creg = fsig(gf) * creg + fsig(gi) * ftanh(gg);
            const float hnew = fsig(go) * ftanh(creg);
            if (frow < RPS) {
                const unsigned short hb2 = f2bf(hnew);
                const unsigned short lb2 = f2bf(hnew - bf2f(hb2));
                const size_t hoff = ((size_t)(wb * NXCD + xcd) * 16
                                     + s * RPS + frow) * Hh + gj;
                hg_hi[hoff] = hb2;
                hg_lo[hoff] = lb2;
            }
        }
        // owner emit partials (reads h(t-1) buffer; must precede flag store)
        if (t >= 2 && owner && ostrm == s)
            emit_partials(hbhi, hblo, t & 1);

        __syncthreads();   // single barrier: drains h stores + xbuf writes

        if (tid == 0)
            *(volatile int*)(fl + fbase + rank) = t;

        // off critical path: fold partials + S1w/S2w recurrence + out store
        if (t >= 2 && tid == 0 && owner && ostrm == s)
            out_update(t - 2, t & 1);
    };

    for (int t = 1; t <= Tt; ++t) {
        half_step(0, t, flags0, creg0);
        half_step(1, t, flags1, creg1);
    }

    // ---- epilogue: out(Tt-1) from h(Tt) buffer (slot 1 avoids slot-0 race) ----
    wave_poll(flags0, Tt);
    wave_poll(flags1, Tt);
    {
        const int rbF = Tt & 1;
        if (owner)
            emit_partials(hg_hi + (size_t)(rbF * NXCD + xcd) * 16 * Hh,
                          hg_lo + (size_t)(rbF * NXCD + xcd) * 16 * Hh, 1);
        __syncthreads();
        if (tid == 0 && owner)
            out_update(Tt - 1, 1);
    }
}

extern "C" void kernel_launch(void* const* d_in, const int* in_sizes, int n_in,
                              void* d_out, int out_size, void* d_ws, size_t ws_size,
                              hipStream_t stream)
{
    const float* xp  = (const float*)d_in[0];
    const float* wih = (const float*)d_in[1];
    const float* whh = (const float*)d_in[2];
    const float* bih = (const float*)d_in[3];
    const float* bhh = (const float*)d_in[4];
    const float* wt  = (const float*)d_in[5];
    const float* wfc = (const float*)d_in[6];
    const float* bfc = (const float*)d_in[7];
    float* outp = (float*)d_out;
    float* ws   = (float*)d_ws;

    // zero flags + counters + BOTH h buffers (h(0)=0; deterministic per call)
    (void)hipMemsetAsync(d_ws, 0, WS_ZERO_B, stream);

    hipLaunchKernelGGL(lstm_fused, dim3(GRID), dim3(THREADS), 0, stream,
                       xp, wih, whh, bih, bhh, wt, wfc, bfc, outp, ws);
}